// Round 14
// baseline (51.860 us; speedup 1.0000x reference)
//
#include <hip/hip_runtime.h>

#define BB 32
#define SS 2048
#define VV 516
#define NBS (BB * SS)      // 65536
#define NCHUNK 16
#define NPART 256          // comb block count

__device__ __forceinline__ float waveReduceSum(float v) {
    #pragma unroll
    for (int o = 32; o > 0; o >>= 1) v += __shfl_down(v, o, 64);
    return v;
}

// Async global -> LDS DMA, 16 B/lane (lane l lands at base + l*16).
__device__ __forceinline__ void stage16(const float* g, float* l) {
    __builtin_amdgcn_global_load_lds(
        (const __attribute__((address_space(1))) void*)(g),
        (__attribute__((address_space(3))) void*)(l),
        16, 0, 0);
}

// One block per (b, v-chunk), 512 threads (8 waves), 2 blocks/CU.
// Single HBM sweep, 4-DEEP DMA PIPELINE (T3/T4: never vmcnt(0) in loop):
//   sub-chunk = 2 rows (16 KB); wave (row=wv>>2, q=wv&3) owns a 2 KB slice.
//   iter k:  vmcnt(4)                 [stage(k) landed; k+1,k+2,k+3 fly on]
//            rowsum(k)                [own slice: LDS read, exp in place,
//                                      write-back, 6-shfl -> ldsQ]
//            lgkmcnt(0); s_barrier    [seal e + ldsQ; DMA NOT drained]
//            stage(k+3) -> buf[(k+3)&3]   (== buf[(k-1)&3])
//            score(k)                 [2 rows x 4 cols from buf[k&3]]
// Hazards: stage(k+3) overwrites buf[(k-1)&3]; its last readers (score(k-1),
// program-order before this iteration's barrier) are sealed.  score(k) reads
// buf[k&3], next overwritten by stage(k+4) at iter k+1 AFTER barrier(k+1).
// rowsum(k) reads only what its own wave's DMA wrote -> vmcnt suffices, no
// barrier.  ldsQ[k&3] rewritten at k+4, 3 barriers after its read.  Steady
// state: 6 DMA instr (96 KB/CU) outstanding continuously -> no convoys.
__global__ __launch_bounds__(512, 2) void hl_tile(const float* __restrict__ x,
                                                  const int* __restrict__ target,
                                                  int* __restrict__ ctr,
                                                  float* __restrict__ pSum,
                                                  float* __restrict__ pBest,
                                                  int* __restrict__ pIdx,
                                                  float* __restrict__ xtArr) {
    __shared__ float buf[4][2][2048];   // 64 KB: 4 bufs x 2 rows
    __shared__ float ldsQ[4][2][4];     // quarter-row sums
    __shared__ float ldsT[8];           // tail-row wave partials

    if (blockIdx.x == 0 && threadIdx.x == 0) ctr[0] = 0;   // comb finalize ctr

    const int c = blockIdx.x & 15, b = blockIdx.x >> 4;
    const int v0 = 32 * c + (c > 12 ? c - 12 : 0);          // 12x32 + 4x33
    const int nv = (c >= 12) ? 33 : 32;
    const int tid = threadIdx.x, lane = tid & 63, wv = tid >> 6;
    const int row = wv >> 2;            // row within sub-chunk (0..1)
    const int q   = wv & 3;             // quarter of the row
    const int s0 = tid << 2;
    const int bs = b * SS + s0;

    int4 tg4 = *(const int4*)(target + bs);
    int tg[4] = {tg4.x, tg4.y, tg4.z, tg4.w};

    float sum[4]  = {0.f, 0.f, 0.f, 0.f};
    float best[4] = {-1.f, -1.f, -1.f, -1.f};
    float xt[4]   = {0.f, 0.f, 0.f, 0.f};
    int   bi[4]   = {v0, v0, v0, v0};

    // wave's global slice base for sub-chunk 0
    const float* gbase = x + (size_t)(b * VV + v0 + row) * SS + q * 512 + lane * 4;

    // ---- prologue: stage sub-chunks 0,1,2 (6 DMA instr/wave in flight) ----
    #pragma unroll
    for (int t = 0; t < 3; ++t) {
        const float* gs = gbase + (size_t)t * 2 * SS;
        float* ls = &buf[t][row][q * 512];
        stage16(gs, ls);
        stage16(gs + 256, ls + 256);
    }

    for (int k = 0; k < 16; ++k) {
        const int kb = k & 3;
        // ---- wait ONLY for stage(k); newer stages stay in flight ----
        if (k <= 13)      { asm volatile("s_waitcnt vmcnt(4)" ::: "memory"); }
        else if (k == 14) { asm volatile("s_waitcnt vmcnt(2)" ::: "memory"); }
        else              { asm volatile("s_waitcnt vmcnt(0)" ::: "memory"); }
        __builtin_amdgcn_sched_barrier(0);
        // ---- rowsum(k): own slice, exp in place ----
        {
            float* p = &buf[kb][row][q * 512 + lane * 4];
            float4 u0 = *(const float4*)p;
            float4 u1 = *(const float4*)(p + 256);
            float4 e0, e1;
            e0.x = __expf(u0.x); e0.y = __expf(u0.y);
            e0.z = __expf(u0.z); e0.w = __expf(u0.w);
            e1.x = __expf(u1.x); e1.y = __expf(u1.y);
            e1.z = __expf(u1.z); e1.w = __expf(u1.w);
            *(float4*)p = e0;
            *(float4*)(p + 256) = e1;
            float a = ((e0.x + e0.y) + (e0.z + e0.w))
                    + ((e1.x + e1.y) + (e1.z + e1.w));
            a = waveReduceSum(a);
            if (lane == 0) ldsQ[kb][row][q] = a;
        }
        // ---- seal e + ldsQ (DMA NOT drained) ----
        asm volatile("s_waitcnt lgkmcnt(0)" ::: "memory");
        __builtin_amdgcn_sched_barrier(0);
        __builtin_amdgcn_s_barrier();
        __builtin_amdgcn_sched_barrier(0);
        // ---- stage(k+3) into buf[(k+3)&3] (safe: readers sealed above) ----
        if (k + 3 < 16) {
            const float* gs = gbase + (size_t)(k + 3) * 2 * SS;
            float* ls = &buf[(k + 3) & 3][row][q * 512];
            stage16(gs, ls);
            stage16(gs + 256, ls + 256);
        }
        // ---- score(k): 2 rows x 4 cols ----
        #pragma unroll
        for (int r = 0; r < 2; ++r) {
            float rs = (ldsQ[kb][r][0] + ldsQ[kb][r][1])
                     + (ldsQ[kb][r][2] + ldsQ[kb][r][3]);
            float rc = 1.f / rs;
            int vg = v0 + k * 2 + r;
            float4 e = *(const float4*)&buf[kb][r][s0];
            sum[0] += e.x; sum[1] += e.y; sum[2] += e.z; sum[3] += e.w;
            float c0 = e.x * rc, c1 = e.y * rc, c2 = e.z * rc, c3 = e.w * rc;
            if (c0 > best[0]) { best[0] = c0; bi[0] = vg; }
            if (c1 > best[1]) { best[1] = c1; bi[1] = vg; }
            if (c2 > best[2]) { best[2] = c2; bi[2] = vg; }
            if (c3 > best[3]) { best[3] = c3; bi[3] = vg; }
        }
        #pragma unroll
        for (int i = 0; i < 4; ++i) {
            int lr = tg[i] - (v0 + k * 2);
            if (lr >= 0 && lr < 2) xt[i] = __logf(buf[kb][lr][s0 + i]);
        }
    }

    if (nv == 33) {   // tail row 32: plain loads, block-wide rowsum
        int vg = v0 + 32;
        float4 xv = *(const float4*)(x + (size_t)(b * VV + vg) * SS + s0);
        float4 e;
        e.x = __expf(xv.x); e.y = __expf(xv.y);
        e.z = __expf(xv.z); e.w = __expf(xv.w);
        float a = waveReduceSum((e.x + e.y) + (e.z + e.w));
        if (lane == 0) ldsT[wv] = a;
        asm volatile("s_waitcnt lgkmcnt(0)" ::: "memory");
        __builtin_amdgcn_sched_barrier(0);
        __builtin_amdgcn_s_barrier();
        float rs = ((ldsT[0] + ldsT[1]) + (ldsT[2] + ldsT[3]))
                 + ((ldsT[4] + ldsT[5]) + (ldsT[6] + ldsT[7]));
        float rc = 1.f / rs;
        if (vg == tg[0]) xt[0] = xv.x;
        if (vg == tg[1]) xt[1] = xv.y;
        if (vg == tg[2]) xt[2] = xv.z;
        if (vg == tg[3]) xt[3] = xv.w;
        sum[0] += e.x; sum[1] += e.y; sum[2] += e.z; sum[3] += e.w;
        float c0 = e.x * rc, c1 = e.y * rc, c2 = e.z * rc, c3 = e.w * rc;
        if (c0 > best[0]) { best[0] = c0; bi[0] = vg; }
        if (c1 > best[1]) { best[1] = c1; bi[1] = vg; }
        if (c2 > best[2]) { best[2] = c2; bi[2] = vg; }
        if (c3 > best[3]) { best[3] = c3; bi[3] = vg; }
    }

    // ---- write per-chunk partials ----
    int o = c * NBS + bs;
    *(float4*)(pSum + o)  = make_float4(sum[0], sum[1], sum[2], sum[3]);
    *(float4*)(pBest + o) = make_float4(best[0], best[1], best[2], best[3]);
    *(int4*)(pIdx + o)    = make_int4(bi[0], bi[1], bi[2], bi[3]);
    int v1 = v0 + nv;
    #pragma unroll
    for (int i = 0; i < 4; ++i)
        if (tg[i] >= v0 && tg[i] < v1) xtArr[bs + i] = xt[i];
}

// Merge chunk partials per (b,s); nll + penalty mask; block partial sums;
// last block folds the 256 partials into the scalar output.  (R3-proven.)
__global__ __launch_bounds__(256) void hl_comb(const int* __restrict__ target,
                                               const int* __restrict__ ttype,
                                               const float* __restrict__ tval,
                                               const float* __restrict__ coeff,
                                               const float* __restrict__ harm,
                                               const float* __restrict__ pSum,
                                               const float* __restrict__ pBest,
                                               const int* __restrict__ pIdx,
                                               const float* __restrict__ xtArr,
                                               float* __restrict__ pNll,
                                               float* __restrict__ pMask,
                                               int* __restrict__ counter,
                                               float* __restrict__ outv) {
    __shared__ float lds[8];
    __shared__ bool isLast;
    int idx = blockIdx.x * 256 + threadIdx.x;            // (b,s) flat

    float sum = 0.f, best = -1e30f;
    int bestIdx = 0;
    #pragma unroll
    for (int c = 0; c < NCHUNK; ++c) {                   // ascending: first-idx ties
        int o = c * NBS + idx;
        sum += pSum[o];
        float sc = pBest[o];
        int ii = pIdx[o];
        if (sc > best) { best = sc; bestIdx = ii; }
    }
    int tgt = target[idx];
    float nll = __logf(sum) - xtArr[idx];

    int pt = ttype[bestIdx], tt = ttype[tgt];
    float pv = tval[bestIdx], tv = tval[tgt];
    float d = fabsf(pv - tv);
    float pw = (d == 7.f) ? harm[0] : (d == 5.f) ? harm[1] : (d == 3.f) ? harm[2]
             : (d == 4.f) ? harm[3] : (d == 1.f) ? harm[4] : (d == 2.f) ? harm[5]
             : harm[6];
    float w = (pt == 0) ? pw
            : (pt == 1) ? coeff[1] * d * (1.f / 160.f)
            : (pt == 2) ? coeff[2] * d * (1.f / 100.f)
            :             coeff[3] * d * (1.f / 128.f);
    float mask = (pt != tt) ? coeff[0] : w;

    int lane = threadIdx.x & 63, wvv = threadIdx.x >> 6;
    float rn = waveReduceSum(nll);
    if (lane == 0) lds[wvv] = rn;
    __syncthreads();
    float totN = (threadIdx.x == 0) ? lds[0] + lds[1] + lds[2] + lds[3] : 0.f;
    __syncthreads();
    float rm = waveReduceSum(mask);
    if (lane == 0) lds[wvv] = rm;
    __syncthreads();
    if (threadIdx.x == 0) {
        pNll[blockIdx.x]  = totN;
        pMask[blockIdx.x] = lds[0] + lds[1] + lds[2] + lds[3];
        __threadfence();
        unsigned old = atomicAdd((unsigned*)counter, 1u);
        isLast = (old == NPART - 1);
    }
    __syncthreads();
    if (isLast) {
        __threadfence();
        int t = threadIdx.x;
        float n = waveReduceSum(pNll[t]);
        float m = waveReduceSum(pMask[t]);
        if (lane == 0) { lds[wvv] = n; lds[4 + wvv] = m; }
        __syncthreads();
        if (t == 0) {
            float tn = lds[0] + lds[1] + lds[2] + lds[3];
            float tm = lds[4] + lds[5] + lds[6] + lds[7];
            const float inv = 1.f / (float)NBS;
            outv[0] = (tn * inv) * (1.f + tm * inv);
        }
    }
}

extern "C" void kernel_launch(void* const* d_in, const int* in_sizes, int n_in,
                              void* d_out, int out_size, void* d_ws, size_t ws_size,
                              hipStream_t stream) {
    const float* x      = (const float*)d_in[0];
    const int*   target = (const int*)d_in[1];
    const int*   ttype  = (const int*)d_in[2];
    const float* tval   = (const float*)d_in[3];
    const float* coeff  = (const float*)d_in[4];
    const float* harm   = (const float*)d_in[5];

    float* ws    = (float*)d_ws;
    int*   ctr   = (int*)ws;                     // 4 ints
    float* pNll  = ws + 4;                       // 256
    float* pMask = pNll + NPART;                 // 256
    float* xtArr = pMask + NPART;                // 65536 (offset 516 -> 16B-aligned)
    float* pSum  = xtArr + NBS;                  // 16*65536
    float* pBest = pSum + (size_t)NCHUNK * NBS;  // 16*65536
    int*   pIdx  = (int*)(pBest + (size_t)NCHUNK * NBS);

    hl_tile<<<BB * NCHUNK, 512, 0, stream>>>(x, target, ctr, pSum, pBest,
                                             pIdx, xtArr);
    hl_comb<<<NBS / 256, 256, 0, stream>>>(target, ttype, tval, coeff, harm,
                                           pSum, pBest, pIdx, xtArr,
                                           pNll, pMask, ctr, (float*)d_out);
}